// Round 9
// baseline (198.674 us; speedup 1.0000x reference)
//
#include <hip/hip_runtime.h>

// x: [T=63, B=1, H=16, S=384, D=128] f32
// y: [T=63, B=1, H=16, D=128, S=384] f32
// out: [63, 1, 16, 384, 384] f32 = broadcast of per-head (mean_t x) @ (mean_t y)
#define T_DIM 63
#define H_DIM 16
#define S_DIM 384
#define D_DIM 128
#define SLICE_ELEMS (H_DIM * S_DIM * D_DIM)        // 786432 floats per t-slice
#define SLICE_F4    (SLICE_ELEMS / 4)              // 196608
#define OUT_TSTRIDE (H_DIM * S_DIM * S_DIM)        // 2359296 floats per t-slice of out
#define W_F4        (OUT_TSTRIDE / 4)              // 589824 float4 per t-slice
#define K3_BLOCKS   768                            // = 3 blocks/CU exactly (balanced)
#define K3_CHUNK_F4 (W_F4 / K3_BLOCKS)             // 768 float4 = 12 KB per block
#define K3_F4_PER_THREAD (K3_CHUNK_F4 / 256)       // 3

typedef float f32x4 __attribute__((ext_vector_type(4)));

// Kernel 1: temporal mean over T for both x and y. Pure read-bound (396 MB).
// nt loads (R7 A/B: nt is worth ~15-20% on these streams).
__global__ __launch_bounds__(256) void treduce_kernel(
    const float* __restrict__ x, const float* __restrict__ y,
    float* __restrict__ xb, float* __restrict__ yb) {
  int tid = blockIdx.x * 256 + threadIdx.x;      // 0 .. 2*SLICE_F4-1
  const f32x4* src;
  f32x4* dst;
  if (tid < SLICE_F4) {
    src = reinterpret_cast<const f32x4*>(x) + tid;
    dst = reinterpret_cast<f32x4*>(xb) + tid;
  } else {
    tid -= SLICE_F4;
    src = reinterpret_cast<const f32x4*>(y) + tid;
    dst = reinterpret_cast<f32x4*>(yb) + tid;
  }
  f32x4 acc = (f32x4)0.f;
#pragma unroll 9
  for (int t = 0; t < T_DIM; ++t) {
    f32x4 v = __builtin_nontemporal_load(src + (size_t)t * SLICE_F4);
    acc += v;
  }
  acc *= (1.0f / (float)T_DIM);
  *dst = acc;
}

// Kernel 2: per-head GEMM w[h] = xb[h] (384x128) @ yb[h] (128x384), computed
// ONCE, written straight into out's t=0 slice. grid=(6,6,16), block=256.
// (byte-identical to R4/R8)
__global__ __launch_bounds__(256) void gemm_kernel(
    const float* __restrict__ xb, const float* __restrict__ yb,
    float* __restrict__ out) {
  __shared__ float As[64][132];   // padded: 2-way max bank aliasing (free)
  __shared__ float Bs[128][64];

  const int h  = blockIdx.z;
  const int by = blockIdx.y;
  const int bx = blockIdx.x;
  const int t  = threadIdx.x;

  const float* A = xb + (size_t)h * S_DIM * D_DIM;  // [384][128] row-major
  const float* B = yb + (size_t)h * D_DIM * S_DIM;  // [128][384] row-major

#pragma unroll
  for (int it = 0; it < 8; ++it) {
    int l = t + it * 256;
    int row = l >> 5;        // 32 float4 per row
    int c4  = l & 31;
    float4 v = *reinterpret_cast<const float4*>(A + (size_t)(by * 64 + row) * D_DIM + c4 * 4);
    *reinterpret_cast<float4*>(&As[row][c4 * 4]) = v;
  }
#pragma unroll
  for (int it = 0; it < 8; ++it) {
    int l = t + it * 256;
    int k  = l >> 4;         // 16 float4 per row
    int c4 = l & 15;
    float4 v = *reinterpret_cast<const float4*>(B + (size_t)k * S_DIM + bx * 64 + c4 * 4);
    *reinterpret_cast<float4*>(&Bs[k][c4 * 4]) = v;
  }
  __syncthreads();

  const int tx = t & 15;
  const int ty = t >> 4;
  const int r0 = ty * 4;
  const int c0 = tx * 4;

  float acc[4][4];
#pragma unroll
  for (int i = 0; i < 4; ++i)
#pragma unroll
    for (int j = 0; j < 4; ++j) acc[i][j] = 0.f;

#pragma unroll 4
  for (int k = 0; k < D_DIM; ++k) {
    float a0 = As[r0 + 0][k];
    float a1 = As[r0 + 1][k];
    float a2 = As[r0 + 2][k];
    float a3 = As[r0 + 3][k];
    float4 b = *reinterpret_cast<const float4*>(&Bs[k][c0]);
    acc[0][0] += a0 * b.x; acc[0][1] += a0 * b.y; acc[0][2] += a0 * b.z; acc[0][3] += a0 * b.w;
    acc[1][0] += a1 * b.x; acc[1][1] += a1 * b.y; acc[1][2] += a1 * b.z; acc[1][3] += a1 * b.w;
    acc[2][0] += a2 * b.x; acc[2][1] += a2 * b.y; acc[2][2] += a2 * b.z; acc[2][3] += a2 * b.w;
    acc[3][0] += a3 * b.x; acc[3][1] += a3 * b.y; acc[3][2] += a3 * b.z; acc[3][3] += a3 * b.w;
  }

  // Write the tile ONCE into the t=0 slice (k3 re-reads it once: 9.4 MB, L2-hot).
  float* o = out + (size_t)h * S_DIM * S_DIM + (size_t)(by * 64 + r0) * S_DIM + bx * 64 + c0;
#pragma unroll
  for (int i = 0; i < 4; ++i) {
    *reinterpret_cast<float4*>(o + (size_t)i * S_DIM) =
        make_float4(acc[i][0], acc[i][1], acc[i][2], acc[i][3]);
  }
}

// Kernel 3: register-resident broadcast. Each of 768 blocks (exactly 3/CU)
// loads its 12 KB chunk of the t=0 slice ONCE into registers (9.4 MB total
// read, L2-dirty from k2), then sweeps t=1..62 t-outer, storing the whole
// chunk per slice visit (3 x 1KB-contiguous nt stores per wave, block covers
// 12 KB contiguous per visit -> near-single-page write locality per visit,
// no interleaved read stream, perfect load balance).
__global__ __launch_bounds__(256) void bcast_kernel(float* __restrict__ out) {
  const int base = blockIdx.x * K3_CHUNK_F4 + threadIdx.x;
  const f32x4* src = reinterpret_cast<const f32x4*>(out);

  f32x4 v[K3_F4_PER_THREAD];
#pragma unroll
  for (int q = 0; q < K3_F4_PER_THREAD; ++q)
    v[q] = src[base + q * 256];

  f32x4* o4 = reinterpret_cast<f32x4*>(out);
#pragma unroll 4
  for (int t = 1; t < T_DIM; ++t) {
    f32x4* dst = o4 + (size_t)t * W_F4 + base;
#pragma unroll
    for (int q = 0; q < K3_F4_PER_THREAD; ++q)
      __builtin_nontemporal_store(v[q], dst + q * 256);
  }
}

extern "C" void kernel_launch(void* const* d_in, const int* in_sizes, int n_in,
                              void* d_out, int out_size, void* d_ws, size_t ws_size,
                              hipStream_t stream) {
  const float* x = (const float*)d_in[0];
  const float* y = (const float*)d_in[1];
  float* out = (float*)d_out;

  float* xb = (float*)d_ws;                 // 786432 floats
  float* yb = xb + SLICE_ELEMS;             // 786432 floats (6 MB total)

  treduce_kernel<<<dim3(2 * SLICE_F4 / 256), dim3(256), 0, stream>>>(x, y, xb, yb);
  gemm_kernel<<<dim3(6, 6, H_DIM), dim3(256), 0, stream>>>(xb, yb, out);
  bcast_kernel<<<dim3(K3_BLOCKS), dim3(256), 0, stream>>>(out);
}

// Round 10
// 184.411 us; speedup vs baseline: 1.0773x; 1.0773x over previous
//
#include <hip/hip_runtime.h>

// x: [T=63, B=1, H=16, S=384, D=128] f32
// y: [T=63, B=1, H=16, D=128, S=384] f32
// out: [63, 1, 16, 384, 384] f32 = broadcast of per-head (mean_t x) @ (mean_t y)
#define T_DIM 63
#define H_DIM 16
#define S_DIM 384
#define D_DIM 128
#define SLICE_ELEMS (H_DIM * S_DIM * D_DIM)        // 786432 floats per t-slice
#define SLICE_F4    (SLICE_ELEMS / 4)              // 196608
#define OUT_TSTRIDE (H_DIM * S_DIM * S_DIM)        // 2359296 floats per t-slice of out
#define W_F4        (OUT_TSTRIDE / 4)              // 589824 float4 per t-slice

typedef float f32x4 __attribute__((ext_vector_type(4)));

// Kernel 1: temporal mean over T for both x and y. Pure read-bound (396 MB).
// nt loads (R7 A/B: nt is worth ~15-20% on these streams). Unchanged from R8.
__global__ __launch_bounds__(256) void treduce_kernel(
    const float* __restrict__ x, const float* __restrict__ y,
    float* __restrict__ xb, float* __restrict__ yb) {
  int tid = blockIdx.x * 256 + threadIdx.x;      // 0 .. 2*SLICE_F4-1
  const f32x4* src;
  f32x4* dst;
  if (tid < SLICE_F4) {
    src = reinterpret_cast<const f32x4*>(x) + tid;
    dst = reinterpret_cast<f32x4*>(xb) + tid;
  } else {
    tid -= SLICE_F4;
    src = reinterpret_cast<const f32x4*>(y) + tid;
    dst = reinterpret_cast<f32x4*>(yb) + tid;
  }
  f32x4 acc = (f32x4)0.f;
#pragma unroll 9
  for (int t = 0; t < T_DIM; ++t) {
    f32x4 v = __builtin_nontemporal_load(src + (size_t)t * SLICE_F4);
    acc += v;
  }
  acc *= (1.0f / (float)T_DIM);
  *dst = acc;
}

// Kernel 2 (NEW this round): lean 32x32-tile GEMM writing only the t=0 slice.
// grid (12,12,16) = 2304 blocks (9/CU, balanced), 18 KB LDS -> 8 blocks/CU.
// Only B staged in LDS; A read direct (8 lanes of a c4-group share one A row
// -> wave-broadcast loads, L1/L2-hot). Thread t: row = t>>3, c4 = t&7.
// Replaces the 64x64 / 66.5KB-LDS k2 whose 2-blocks/CU occupancy + 1.125
// occupancy-wave tail made it ~15-20 us.
__global__ __launch_bounds__(256) void gemm_kernel(
    const float* __restrict__ xb, const float* __restrict__ yb,
    float* __restrict__ out) {
  __shared__ float Bs[128][36];

  const int h  = blockIdx.z;
  const int by = blockIdx.y;
  const int bx = blockIdx.x;
  const int t  = threadIdx.x;

  const float* A = xb + (size_t)h * S_DIM * D_DIM;  // [384][128] row-major
  const float* B = yb + (size_t)h * D_DIM * S_DIM;  // [128][384] row-major

  // Stage B tile: 128 rows x 32 cols = 1024 float4, 4 per thread.
#pragma unroll
  for (int it = 0; it < 4; ++it) {
    int l = t + it * 256;
    int k  = l >> 3;         // 8 float4 per row
    int c4 = l & 7;
    float4 v = *reinterpret_cast<const float4*>(B + (size_t)k * S_DIM + bx * 32 + c4 * 4);
    *reinterpret_cast<float4*>(&Bs[k][c4 * 4]) = v;
  }
  __syncthreads();

  const int row = t >> 3;   // 0..31
  const int c4  = t & 7;    // 0..7

  const f32x4* A4 = reinterpret_cast<const f32x4*>(A + (size_t)(by * 32 + row) * D_DIM);

  f32x4 acc = (f32x4)0.f;
#pragma unroll 8
  for (int k4 = 0; k4 < 32; ++k4) {
    f32x4 a4 = A4[k4];
    f32x4 b0 = *reinterpret_cast<const f32x4*>(&Bs[k4 * 4 + 0][c4 * 4]);
    f32x4 b1 = *reinterpret_cast<const f32x4*>(&Bs[k4 * 4 + 1][c4 * 4]);
    f32x4 b2 = *reinterpret_cast<const f32x4*>(&Bs[k4 * 4 + 2][c4 * 4]);
    f32x4 b3 = *reinterpret_cast<const f32x4*>(&Bs[k4 * 4 + 3][c4 * 4]);
    acc += a4.x * b0;
    acc += a4.y * b1;
    acc += a4.z * b2;
    acc += a4.w * b3;
  }

  // Write ONCE into the t=0 slice (plain store: k3 re-reads it, keep cached).
  float* o = out + (size_t)h * S_DIM * S_DIM
                 + (size_t)(by * 32 + row) * S_DIM + bx * 32 + c4 * 4;
  *reinterpret_cast<f32x4*>(o) = acc;
}

// Kernel 3: pure broadcast, fill geometry (t-major) — unchanged from R8.
// Block (cx, ty) owns a linear 16KB chunk of t-slice ty+1; 4 cached reads of
// the t=0 slice + 4 nt stores, 1KB contiguous per store instr. All 62 copies
// of chunk cx land on the same XCD (576 % 8 == 0) -> w reads L2-resident.
// grid = (576, 62), block = 256.
__global__ __launch_bounds__(256) void bcast_kernel(float* __restrict__ out) {
  const int i0 = blockIdx.x * 1024 + threadIdx.x;        // chunk base + lane
  const size_t toff = (size_t)(blockIdx.y + 1) * W_F4;   // t = 1..62
  const f32x4* src = reinterpret_cast<const f32x4*>(out);
  f32x4* dst = reinterpret_cast<f32x4*>(out) + toff;
#pragma unroll
  for (int q = 0; q < 4; ++q) {
    int i = i0 + q * 256;
    f32x4 v = src[i];
    __builtin_nontemporal_store(v, dst + i);
  }
}

extern "C" void kernel_launch(void* const* d_in, const int* in_sizes, int n_in,
                              void* d_out, int out_size, void* d_ws, size_t ws_size,
                              hipStream_t stream) {
  const float* x = (const float*)d_in[0];
  const float* y = (const float*)d_in[1];
  float* out = (float*)d_out;

  float* xb = (float*)d_ws;                 // 786432 floats
  float* yb = xb + SLICE_ELEMS;             // 786432 floats (6 MB total)

  treduce_kernel<<<dim3(2 * SLICE_F4 / 256), dim3(256), 0, stream>>>(x, y, xb, yb);
  gemm_kernel<<<dim3(12, 12, H_DIM), dim3(256), 0, stream>>>(xb, yb, out);
  bcast_kernel<<<dim3(W_F4 / 1024, T_DIM - 1), dim3(256), 0, stream>>>(out);
}

// Round 11
// 181.685 us; speedup vs baseline: 1.0935x; 1.0150x over previous
//
#include <hip/hip_runtime.h>

// x: [T=63, B=1, H=16, S=384, D=128] f32
// y: [T=63, B=1, H=16, D=128, S=384] f32
// out: [63, 1, 16, 384, 384] f32 = broadcast of per-head (mean_t x) @ (mean_t y)
#define T_DIM 63
#define H_DIM 16
#define S_DIM 384
#define D_DIM 128
#define SLICE_ELEMS (H_DIM * S_DIM * D_DIM)        // 786432 floats per t-slice
#define SLICE_F4    (SLICE_ELEMS / 4)              // 196608
#define OUT_TSTRIDE (H_DIM * S_DIM * S_DIM)        // 2359296 floats per t-slice of out
#define W_F4        (OUT_TSTRIDE / 4)              // 589824 float4 per t-slice

typedef float f32x4 __attribute__((ext_vector_type(4)));

// Kernel 1: temporal mean over T for both x and y. Pure read-bound (396 MB).
// nt loads (R7 A/B: nt worth ~15-20% on these streams). Unchanged from R8/R10.
__global__ __launch_bounds__(256) void treduce_kernel(
    const float* __restrict__ x, const float* __restrict__ y,
    float* __restrict__ xb, float* __restrict__ yb) {
  int tid = blockIdx.x * 256 + threadIdx.x;      // 0 .. 2*SLICE_F4-1
  const f32x4* src;
  f32x4* dst;
  if (tid < SLICE_F4) {
    src = reinterpret_cast<const f32x4*>(x) + tid;
    dst = reinterpret_cast<f32x4*>(xb) + tid;
  } else {
    tid -= SLICE_F4;
    src = reinterpret_cast<const f32x4*>(y) + tid;
    dst = reinterpret_cast<f32x4*>(yb) + tid;
  }
  f32x4 acc = (f32x4)0.f;
#pragma unroll 9
  for (int t = 0; t < T_DIM; ++t) {
    f32x4 v = __builtin_nontemporal_load(src + (size_t)t * SLICE_F4);
    acc += v;
  }
  acc *= (1.0f / (float)T_DIM);
  *dst = acc;
}

// Kernel 2: lean 32x32-tile GEMM writing only the t=0 slice (as R10), but the
// w store is NONTEMPORAL this round: plain stores leave w dirty in the writer
// XCD's L2, and k3's readers on the other 7 XCDs then hit cross-XCD
// dirty-line resolution (writeback via L3) at the head of every copy. nt
// pushes w straight to L3/HBM at write time -> k3 reads are clean hits.
__global__ __launch_bounds__(256) void gemm_kernel(
    const float* __restrict__ xb, const float* __restrict__ yb,
    float* __restrict__ out) {
  __shared__ float Bs[128][36];

  const int h  = blockIdx.z;
  const int by = blockIdx.y;
  const int bx = blockIdx.x;
  const int t  = threadIdx.x;

  const float* A = xb + (size_t)h * S_DIM * D_DIM;  // [384][128] row-major
  const float* B = yb + (size_t)h * D_DIM * S_DIM;  // [128][384] row-major

  // Stage B tile: 128 rows x 32 cols = 1024 float4, 4 per thread.
#pragma unroll
  for (int it = 0; it < 4; ++it) {
    int l = t + it * 256;
    int k  = l >> 3;         // 8 float4 per row
    int c4 = l & 7;
    float4 v = *reinterpret_cast<const float4*>(B + (size_t)k * S_DIM + bx * 32 + c4 * 4);
    *reinterpret_cast<float4*>(&Bs[k][c4 * 4]) = v;
  }
  __syncthreads();

  const int row = t >> 3;   // 0..31
  const int c4  = t & 7;    // 0..7

  const f32x4* A4 = reinterpret_cast<const f32x4*>(A + (size_t)(by * 32 + row) * D_DIM);

  f32x4 acc = (f32x4)0.f;
#pragma unroll 8
  for (int k4 = 0; k4 < 32; ++k4) {
    f32x4 a4 = A4[k4];
    f32x4 b0 = *reinterpret_cast<const f32x4*>(&Bs[k4 * 4 + 0][c4 * 4]);
    f32x4 b1 = *reinterpret_cast<const f32x4*>(&Bs[k4 * 4 + 1][c4 * 4]);
    f32x4 b2 = *reinterpret_cast<const f32x4*>(&Bs[k4 * 4 + 2][c4 * 4]);
    f32x4 b3 = *reinterpret_cast<const f32x4*>(&Bs[k4 * 4 + 3][c4 * 4]);
    acc += a4.x * b0;
    acc += a4.y * b1;
    acc += a4.z * b2;
    acc += a4.w * b3;
  }

  // Write ONCE into the t=0 slice — NT store (the round's single variable).
  float* o = out + (size_t)h * S_DIM * S_DIM
                 + (size_t)(by * 32 + row) * S_DIM + bx * 32 + c4 * 4;
  __builtin_nontemporal_store(acc, reinterpret_cast<f32x4*>(o));
}

// Kernel 3: pure broadcast, fill geometry (t-major) — unchanged from R8/R10.
// grid = (576, 62), block = 256; 4 cached reads of t=0 + 4 nt stores (1KB
// contiguous per store instr per wave).
__global__ __launch_bounds__(256) void bcast_kernel(float* __restrict__ out) {
  const int i0 = blockIdx.x * 1024 + threadIdx.x;        // chunk base + lane
  const size_t toff = (size_t)(blockIdx.y + 1) * W_F4;   // t = 1..62
  const f32x4* src = reinterpret_cast<const f32x4*>(out);
  f32x4* dst = reinterpret_cast<f32x4*>(out) + toff;
#pragma unroll
  for (int q = 0; q < 4; ++q) {
    int i = i0 + q * 256;
    f32x4 v = src[i];
    __builtin_nontemporal_store(v, dst + i);
  }
}

extern "C" void kernel_launch(void* const* d_in, const int* in_sizes, int n_in,
                              void* d_out, int out_size, void* d_ws, size_t ws_size,
                              hipStream_t stream) {
  const float* x = (const float*)d_in[0];
  const float* y = (const float*)d_in[1];
  float* out = (float*)d_out;

  float* xb = (float*)d_ws;                 // 786432 floats
  float* yb = xb + SLICE_ELEMS;             // 786432 floats (6 MB total)

  treduce_kernel<<<dim3(2 * SLICE_F4 / 256), dim3(256), 0, stream>>>(x, y, xb, yb);
  gemm_kernel<<<dim3(12, 12, H_DIM), dim3(256), 0, stream>>>(xb, yb, out);
  bcast_kernel<<<dim3(W_F4 / 1024, T_DIM - 1), dim3(256), 0, stream>>>(out);
}